// Round 14
// baseline (266.123 us; speedup 1.0000x reference)
//
#include <hip/hip_runtime.h>
#include <hip/hip_bf16.h>

#define THREADS 1024   // 16 waves/block, one block/CU -> 4 waves/SIMD co-resident

typedef short bf16x8 __attribute__((ext_vector_type(8)));
typedef float f32x4 __attribute__((ext_vector_type(4)));

union FragU { unsigned u[4]; bf16x8 v; };

// ---- split f32x8 into bf16 hi/lo fragments (hi=rne(x), lo=rne(x-hi)) ----
__device__ __forceinline__ void split8(const float* x, FragU& hi, FragU& lo) {
#pragma unroll
    for (int i = 0; i < 4; ++i) {
        float a = x[2 * i], b = x[2 * i + 1];
        __hip_bfloat162 h2 = __float22bfloat162_rn(make_float2(a, b));
        float ra = __bfloat162float(h2.x), rb = __bfloat162float(h2.y);
        __hip_bfloat162 l2 = __float22bfloat162_rn(make_float2(a - ra, b - rb));
        unsigned hu, lu;
        __builtin_memcpy(&hu, &h2, 4);
        __builtin_memcpy(&lu, &l2, 4);
        hi.u[i] = hu; lo.u[i] = lu;
    }
}

// ---- 3-product split-bf16 MFMA: D += (Ah+Al)(Bh+Bl) - Al*Bl ----
__device__ __forceinline__ f32x4 mm3(const FragU& ah, const FragU& al,
                                     const FragU& bh, const FragU& bl, f32x4 acc) {
    acc = __builtin_amdgcn_mfma_f32_16x16x32_bf16(al.v, bh.v, acc, 0, 0, 0);
    acc = __builtin_amdgcn_mfma_f32_16x16x32_bf16(ah.v, bl.v, acc, 0, 0, 0);
    acc = __builtin_amdgcn_mfma_f32_16x16x32_bf16(ah.v, bh.v, acc, 0, 0, 0);
    return acc;
}

__device__ __forceinline__ void load_pair(const uint4* __restrict__ ws, int pair, int lane,
                                          FragU& hi, FragU& lo) {
    uint4 a = ws[pair * 128 + lane];
    uint4 b = ws[pair * 128 + 64 + lane];
    hi.u[0] = a.x; hi.u[1] = a.y; hi.u[2] = a.z; hi.u[3] = a.w;
    lo.u[0] = b.x; lo.u[1] = b.y; lo.u[2] = b.z; lo.u[3] = b.w;
}

// A frag from LDS row-major (stride dwords): row=lane&15 (+m*16), k=(lane>>4)*8+j
__device__ __forceinline__ void buildA(const float* buf, int stride, int m, int kf, int lane,
                                       FragU& hi, FragU& lo) {
    const float* p = buf + (m * 16 + (lane & 15)) * stride + kf * 32 + ((lane >> 4) * 8);
    float x[8];
    *reinterpret_cast<float4*>(&x[0]) = *reinterpret_cast<const float4*>(p);
    *reinterpret_cast<float4*>(&x[4]) = *reinterpret_cast<const float4*>(p + 4);
    split8(x, hi, lo);
}

// C frag to LDS row-major: col=lane&15 (+nf*16), row=(lane>>4)*4+q (+m*16)
__device__ __forceinline__ void storeC(float* buf, int stride, int m, int nf, int lane, f32x4 c) {
    float* p = buf + (((lane >> 4) * 4) + m * 16) * stride + nf * 16 + (lane & 15);
    p[0] = c[0]; p[stride] = c[1]; p[2 * stride] = c[2]; p[3 * stride] = c[3];
}

// pair table: pair = base + kf*NF + nf   (same as R6-R13, prep unchanged)
#define PB_D2  0
#define PB_T1  2
#define PB_T2  4
#define PB_P1T 6
#define PB_P1B 10
#define PB_P2  18
#define PB_V1  20
#define PB_V2  28
#define PB_S1  32
#define WS_BYTES (36 * 2048)

__global__ __launch_bounds__(64)
void prep_weights(const float* __restrict__ wd2, const float* __restrict__ wt1,
                  const float* __restrict__ wt2, const float* __restrict__ wp1,
                  const float* __restrict__ wp2, const float* __restrict__ wv1,
                  const float* __restrict__ wv2, const float* __restrict__ ws1,
                  uint4* __restrict__ wsout) {
    const int pair = blockIdx.x;
    const int lane = threadIdx.x;
    const int base_[10]  = {0, 2, 4, 6, 10, 18, 20, 28, 32, 36};
    const int kreal_[9]  = {32, 18, 32, 32, 53, 64, 53, 64, 53};
    const int n_[9]      = {32, 32, 32, 64, 64, 16, 64, 32, 32};
    const int nfc_[9]    = {2, 2, 2, 4, 4, 1, 4, 2, 2};
    const int roff_[9]   = {0, 0, 0, 0, 32, 0, 0, 0, 0};
    int g = 0;
    while (g < 8 && pair >= base_[g + 1]) ++g;
    const int local = pair - base_[g];
    const int kf = local / nfc_[g];
    const int nfi = local % nfc_[g];
    const float* W = (g == 0) ? wd2 : (g == 1) ? wt1 : (g == 2) ? wt2 :
                     (g == 3 || g == 4) ? wp1 : (g == 5) ? wp2 :
                     (g == 6) ? wv1 : (g == 7) ? wv2 : ws1;
    const int N = n_[g];
    float x[8];
#pragma unroll
    for (int j = 0; j < 8; ++j) {
        const int k = kf * 32 + (lane >> 4) * 8 + j;
        const int n = nfi * 16 + (lane & 15);
        x[j] = (k < kreal_[g]) ? W[(roff_[g] + k) * N + n] : 0.0f;
    }
    FragU hi, lo;
    split8(x, hi, lo);
    wsout[pair * 128 + lane]      = make_uint4(hi.u[0], hi.u[1], hi.u[2], hi.u[3]);
    wsout[pair * 128 + 64 + lane] = make_uint4(lo.u[0], lo.u[1], lo.u[2], lo.u[3]);
}

#define SB 68
#define SS 36
// 32 rows/wave (m=2), R11 sequential structure. Per-wave LDS region = 2304 f:
//   phase 1: BASE[32][68] = 2176 f (cols 0..52 data, 53..63 zero K-pad)
//   phase 2: BUFA[32][36] (0..1151) + BUFB[32][36] (1152..2303), ALIASED on BASE
// 16 waves x 9216 B = 147456 B -> one 16-wave block/CU = 4 WAVES/SIMD.
// (R8: separate blocks never co-schedule; R9: waves of one block must.
//  flat-1024 VGPR budget = 512/4 = 128; R11 measured 120 -> fits, no spill.)
#define WAVE_F 2304

__global__ __launch_bounds__(THREADS)   // plain: min-waves attr triggers demotion (R3/R4/R10)
void dueling_mfma(const float* __restrict__ state, const float* __restrict__ emb,
                  const float* __restrict__ wd1, const float* __restrict__ bd1,
                  const float* __restrict__ bd2, const float* __restrict__ bt1,
                  const float* __restrict__ bt2, const float* __restrict__ bv1,
                  const float* __restrict__ bv2, const float* __restrict__ wv3,
                  const float* __restrict__ bv3, const float* __restrict__ bs1,
                  const float* __restrict__ ws2, const float* __restrict__ bs2,
                  const float* __restrict__ bp1, const float* __restrict__ bp2,
                  const float* __restrict__ wp3,
                  const uint4* __restrict__ ws, float* __restrict__ out, int nrows) {
    __shared__ float smem[16 * WAVE_F];   // 147456 B
    const int lane = threadIdx.x & 63;
    const int wave = threadIdx.x >> 6;    // 0..15
    const int r    = lane & 31;           // row within wave tile
    const int sub  = lane >> 5;           // sublane for split staging
    const int row  = blockIdx.x * 512 + wave * 32 + r;
    const float* __restrict__ s = state + (long long)row * 78;

    float* BASE = smem + wave * WAVE_F;
    float* BUFA = BASE;                   // phase-2 alias (BASE dead after X hoist)
    float* BUFB = BASE + 32 * SS;         // +1152 floats
    float* HST  = BASE + 24;              // defender h staging (cols 24..55)
    const int c16 = lane & 15;

    // zero whole wave region: 2304 f = 9 x (64 lanes x float4)
#pragma unroll
    for (int i = 0; i < 9; ++i)
        *reinterpret_cast<float4*>(BASE + i * 256 + lane * 4) = make_float4(0.f, 0.f, 0.f, 0.f);

    //=========== per-lane features -> BASE cols 0..20 (lanes 0..31, one per row) ===========
    if (lane < 32) {
        int pid0 = (int)s[73];
        pid0 = pid0 < 0 ? 0 : (pid0 > 449 ? 449 : pid0);
        const float4 e0 = *(const float4*)(emb + pid0 * 8);
        const float4 e1 = *(const float4*)(emb + pid0 * 8 + 4);
        float* bp = BASE + r * SB;
        *reinterpret_cast<float4*>(bp +  0) = make_float4(s[0], s[1], s[2], s[3]);
        *reinterpret_cast<float4*>(bp +  4) = make_float4(s[4], s[5], s[6], s[7]);
        *reinterpret_cast<float4*>(bp +  8) = make_float4(s[8], s[9], s[10], s[41]);
        *reinterpret_cast<float4*>(bp + 12) = make_float4(s[42], e0.x, e0.y, e0.z);
        *reinterpret_cast<float4*>(bp + 16) = make_float4(e0.w, e1.x, e1.y, e1.z);
        bp[20] = e1.w;
    }

    //=========== defender head: d1 split across sublanes (branchless), d2 MFMA ===========
    float pool[2][2][4];
#pragma unroll
    for (int m = 0; m < 2; ++m)
#pragma unroll
        for (int nf = 0; nf < 2; ++nf)
#pragma unroll
            for (int q = 0; q < 4; ++q) pool[m][nf][q] = 0.0f;

#pragma unroll 1
    for (int p = 0; p < 5; ++p) {
        const float f0 = s[23 + 2 * p], f1 = s[24 + 2 * p];
        const float f2 = s[43 + 2 * p], f3 = s[44 + 2 * p];
#pragma unroll
        for (int i2 = 0; i2 < 4; ++i2) {
            const int i = sub * 4 + i2;          // sublane 0: n 0..15, sublane 1: n 16..31
            const float4 b4 = *(const float4*)(bd1 + i * 4);
            const float4 w0 = *(const float4*)(wd1 + 0 * 32 + i * 4);
            const float4 w1 = *(const float4*)(wd1 + 1 * 32 + i * 4);
            const float4 w2 = *(const float4*)(wd1 + 2 * 32 + i * 4);
            const float4 w3 = *(const float4*)(wd1 + 3 * 32 + i * 4);
            float4 hv;
            hv.x = fmaxf(fmaf(f0, w0.x, fmaf(f1, w1.x, fmaf(f2, w2.x, fmaf(f3, w3.x, b4.x)))), 0.f);
            hv.y = fmaxf(fmaf(f0, w0.y, fmaf(f1, w1.y, fmaf(f2, w2.y, fmaf(f3, w3.y, b4.y)))), 0.f);
            hv.z = fmaxf(fmaf(f0, w0.z, fmaf(f1, w1.z, fmaf(f2, w2.z, fmaf(f3, w3.z, b4.z)))), 0.f);
            hv.w = fmaxf(fmaf(f0, w0.w, fmaf(f1, w1.w, fmaf(f2, w2.w, fmaf(f3, w3.w, b4.w)))), 0.f);
            *reinterpret_cast<float4*>(BASE + r * SB + 24 + i * 4) = hv;
        }

        FragU ah[2], al[2];
#pragma unroll
        for (int m = 0; m < 2; ++m) buildA(HST, SB, m, 0, lane, ah[m], al[m]);
#pragma unroll
        for (int nf = 0; nf < 2; ++nf) {
            FragU bh, bl; load_pair(ws, PB_D2 + nf, lane, bh, bl);
            const float bias = bd2[nf * 16 + c16];
#pragma unroll
            for (int m = 0; m < 2; ++m) {
                f32x4 acc = {bias, bias, bias, bias};
                acc = mm3(ah[m], al[m], bh, bl, acc);
#pragma unroll
                for (int q = 0; q < 4; ++q) pool[m][nf][q] += fmaxf(acc[q], 0.0f);
            }
        }
    }
    // re-zero K-pad cols 53..55 dirtied by h staging (both sublanes write 0: benign)
    BASE[r * SB + 53] = 0.0f;
    BASE[r * SB + 54] = 0.0f;
    BASE[r * SB + 55] = 0.0f;
    // pooled/5 -> BASE cols 21..52 (C-layout writes, rows 0..31)
#pragma unroll
    for (int m = 0; m < 2; ++m)
#pragma unroll
        for (int nf = 0; nf < 2; ++nf)
#pragma unroll
            for (int q = 0; q < 4; ++q)
                BASE[((lane >> 4) * 4 + q + m * 16) * SB + 21 + nf * 16 + c16] =
                    pool[m][nf][q] * 0.2f;

    //=========== HOIST: BASE A-fragments (4 pairs = 32 VGPR; BASE LDS dead after) ===========
    FragU Xh[2][2], Xl[2][2];
#pragma unroll
    for (int m = 0; m < 2; ++m)
#pragma unroll
        for (int kf = 0; kf < 2; ++kf)
            buildA(BASE, SB, m, kf, lane, Xh[m][kf], Xl[m][kf]);

    //=========== value head ===========
    float v2acc[2][2][4];
#pragma unroll
    for (int m = 0; m < 2; ++m)
#pragma unroll
        for (int nf = 0; nf < 2; ++nf) {
            const float b = bv2[nf * 16 + c16];
#pragma unroll
            for (int q = 0; q < 4; ++q) v2acc[m][nf][q] = b;
        }
#pragma unroll 1
    for (int half = 0; half < 2; ++half) {
#pragma unroll
        for (int nfl = 0; nfl < 2; ++nfl) {
            const int ng = half * 2 + nfl;
            FragU b0h, b0l, b1h, b1l;
            load_pair(ws, PB_V1 + ng, lane, b0h, b0l);
            load_pair(ws, PB_V1 + 4 + ng, lane, b1h, b1l);
            const float bias = bv1[ng * 16 + c16];
#pragma unroll
            for (int m = 0; m < 2; ++m) {
                f32x4 acc = {bias, bias, bias, bias};
                acc = mm3(Xh[m][0], Xl[m][0], b0h, b0l, acc);
                acc = mm3(Xh[m][1], Xl[m][1], b1h, b1l, acc);
#pragma unroll
                for (int q = 0; q < 4; ++q) acc[q] = fmaxf(acc[q], 0.0f);
                storeC(BUFA, SS, m, nfl, lane, acc);
            }
        }
        FragU ah[2], al[2];
#pragma unroll
        for (int m = 0; m < 2; ++m) buildA(BUFA, SS, m, 0, lane, ah[m], al[m]);
#pragma unroll
        for (int nf = 0; nf < 2; ++nf) {
            FragU bh, bl; load_pair(ws, PB_V2 + half * 2 + nf, lane, bh, bl);
#pragma unroll
            for (int m = 0; m < 2; ++m) {
                f32x4 acc = {v2acc[m][nf][0], v2acc[m][nf][1], v2acc[m][nf][2], v2acc[m][nf][3]};
                acc = mm3(ah[m], al[m], bh, bl, acc);
#pragma unroll
                for (int q = 0; q < 4; ++q) v2acc[m][nf][q] = acc[q];
            }
        }
    }
#pragma unroll
    for (int m = 0; m < 2; ++m)
#pragma unroll
        for (int nf = 0; nf < 2; ++nf) {
            f32x4 rr = {fmaxf(v2acc[m][nf][0], 0.f), fmaxf(v2acc[m][nf][1], 0.f),
                        fmaxf(v2acc[m][nf][2], 0.f), fmaxf(v2acc[m][nf][3], 0.f)};
            storeC(BUFA, SS, m, nf, lane, rr);
        }
    float value = bv3[0];
#pragma unroll
    for (int c4 = 0; c4 < 8; ++c4) {
        float4 v = *reinterpret_cast<const float4*>(BUFA + r * SS + c4 * 4);
        value = fmaf(v.x, wv3[c4 * 4], value);
        value = fmaf(v.y, wv3[c4 * 4 + 1], value);
        value = fmaf(v.z, wv3[c4 * 4 + 2], value);
        value = fmaf(v.w, wv3[c4 * 4 + 3], value);
    }

    //=========== shoot head (uses hoisted X frags) ===========
#pragma unroll
    for (int nf = 0; nf < 2; ++nf) {
        FragU b0h, b0l, b1h, b1l;
        load_pair(ws, PB_S1 + nf, lane, b0h, b0l);
        load_pair(ws, PB_S1 + 2 + nf, lane, b1h, b1l);
        const float bias = bs1[nf * 16 + c16];
#pragma unroll
        for (int m = 0; m < 2; ++m) {
            f32x4 acc = {bias, bias, bias, bias};
            acc = mm3(Xh[m][0], Xl[m][0], b0h, b0l, acc);
            acc = mm3(Xh[m][1], Xl[m][1], b1h, b1l, acc);
#pragma unroll
            for (int q = 0; q < 4; ++q) acc[q] = fmaxf(acc[q], 0.0f);
            storeC(BUFA, SS, m, nf, lane, acc);
        }
    }
    float ashoot = bs2[0];
#pragma unroll
    for (int c4 = 0; c4 < 8; ++c4) {
        float4 v = *reinterpret_cast<const float4*>(BUFA + r * SS + c4 * 4);
        ashoot = fmaf(v.x, ws2[c4 * 4], ashoot);
        ashoot = fmaf(v.y, ws2[c4 * 4 + 1], ashoot);
        ashoot = fmaf(v.z, ws2[c4 * 4 + 2], ashoot);
        ashoot = fmaf(v.w, ws2[c4 * 4 + 3], ashoot);
    }

    //=========== teammates (sequential, R11 structure) ===========
    float ap0 = 0.f, ap1 = 0.f, ap2 = 0.f, ap3 = 0.f;
#pragma unroll 1
    for (int j = 0; j < 4; ++j) {
        if (lane < 32) {
            int pid = (int)s[74 + j];
            pid = pid < 0 ? 0 : (pid > 449 ? 449 : pid);
            const float4 e0 = *(const float4*)(emb + pid * 8);
            const float4 e1 = *(const float4*)(emb + pid * 8 + 4);
            float* tp = BUFA + r * SS;
            *reinterpret_cast<float4*>(tp +  0) =
                make_float4(s[33 + 2 * j], s[34 + 2 * j], s[53 + 2 * j], s[54 + 2 * j]);
            *reinterpret_cast<float4*>(tp +  4) =
                make_float4(s[11 + j], s[15 + j], s[19 + j], s[61 + j]);
            *reinterpret_cast<float4*>(tp +  8) = make_float4(s[65 + j], s[69 + j], e0.x, e0.y);
            *reinterpret_cast<float4*>(tp + 12) = make_float4(e0.z, e0.w, e1.x, e1.y);
            *reinterpret_cast<float4*>(tp + 16) = make_float4(e1.z, e1.w, 0.f, 0.f);
            *reinterpret_cast<float4*>(tp + 20) = make_float4(0.f, 0.f, 0.f, 0.f);
            *reinterpret_cast<float4*>(tp + 24) = make_float4(0.f, 0.f, 0.f, 0.f);
            *reinterpret_cast<float4*>(tp + 28) = make_float4(0.f, 0.f, 0.f, 0.f);
        }
        // t1: BUFA -> BUFB
        {
            FragU ah[2], al[2];
#pragma unroll
            for (int m = 0; m < 2; ++m) buildA(BUFA, SS, m, 0, lane, ah[m], al[m]);
#pragma unroll
            for (int nf = 0; nf < 2; ++nf) {
                FragU bh, bl; load_pair(ws, PB_T1 + nf, lane, bh, bl);
                const float bias = bt1[nf * 16 + c16];
#pragma unroll
                for (int m = 0; m < 2; ++m) {
                    f32x4 acc = {bias, bias, bias, bias};
                    acc = mm3(ah[m], al[m], bh, bl, acc);
#pragma unroll
                    for (int q = 0; q < 4; ++q) acc[q] = fmaxf(acc[q], 0.0f);
                    storeC(BUFB, SS, m, nf, lane, acc);
                }
            }
        }
        // t2: BUFB -> BUFA
        {
            FragU ah[2], al[2];
#pragma unroll
            for (int m = 0; m < 2; ++m) buildA(BUFB, SS, m, 0, lane, ah[m], al[m]);
#pragma unroll
            for (int nf = 0; nf < 2; ++nf) {
                FragU bh, bl; load_pair(ws, PB_T2 + nf, lane, bh, bl);
                const float bias = bt2[nf * 16 + c16];
#pragma unroll
                for (int m = 0; m < 2; ++m) {
                    f32x4 acc = {bias, bias, bias, bias};
                    acc = mm3(ah[m], al[m], bh, bl, acc);
#pragma unroll
                    for (int q = 0; q < 4; ++q) acc[q] = fmaxf(acc[q], 0.0f);
                    storeC(BUFA, SS, m, nf, lane, acc);
                }
            }
        }
        // hoist t2 frags for p1t (reused across half & nfl)
        FragU th[2], tl2[2];
#pragma unroll
        for (int m = 0; m < 2; ++m) buildA(BUFA, SS, m, 0, lane, th[m], tl2[m]);

        float p2acc[2][4];
        {
            const float bq = bp2[c16];
#pragma unroll
            for (int m = 0; m < 2; ++m)
#pragma unroll
                for (int q = 0; q < 4; ++q) p2acc[m][q] = bq;
        }
#pragma unroll 1
        for (int half = 0; half < 2; ++half) {
#pragma unroll
            for (int nfl = 0; nfl < 2; ++nfl) {
                const int ng = half * 2 + nfl;
                FragU bth, btl, b0h, b0l, b1h, b1l;
                load_pair(ws, PB_P1T + ng, lane, bth, btl);
                load_pair(ws, PB_P1B + ng, lane, b0h, b0l);
                load_pair(ws, PB_P1B + 4 + ng, lane, b1h, b1l);
                const float bias = bp1[ng * 16 + c16];
#pragma unroll
                for (int m = 0; m < 2; ++m) {
                    f32x4 acc = {bias, bias, bias, bias};
                    acc = mm3(th[m], tl2[m], bth, btl, acc);
                    acc = mm3(Xh[m][0], Xl[m][0], b0h, b0l, acc);
                    acc = mm3(Xh[m][1], Xl[m][1], b1h, b1l, acc);
#pragma unroll
                    for (int q = 0; q < 4; ++q) acc[q] = fmaxf(acc[q], 0.0f);
                    storeC(BUFB, SS, m, nfl, lane, acc);
                }
            }
            FragU bh, bl; load_pair(ws, PB_P2 + half, lane, bh, bl);
#pragma unroll
            for (int m = 0; m < 2; ++m) {
                FragU ah, al; buildA(BUFB, SS, m, 0, lane, ah, al);
                f32x4 acc = {p2acc[m][0], p2acc[m][1], p2acc[m][2], p2acc[m][3]};
                acc = mm3(ah, al, bh, bl, acc);
#pragma unroll
                for (int q = 0; q < 4; ++q) p2acc[m][q] = acc[q];
            }
        }
#pragma unroll
        for (int m = 0; m < 2; ++m) {
            f32x4 rr = {fmaxf(p2acc[m][0], 0.f), fmaxf(p2acc[m][1], 0.f),
                        fmaxf(p2acc[m][2], 0.f), fmaxf(p2acc[m][3], 0.f)};
            storeC(BUFB, SS, m, 0, lane, rr);
        }
        float ap = 0.0f;
#pragma unroll
        for (int c4 = 0; c4 < 4; ++c4) {
            float4 v = *reinterpret_cast<const float4*>(BUFB + r * SS + c4 * 4);
            ap = fmaf(v.x, wp3[c4 * 4], ap);
            ap = fmaf(v.y, wp3[c4 * 4 + 1], ap);
            ap = fmaf(v.z, wp3[c4 * 4 + 2], ap);
            ap = fmaf(v.w, wp3[c4 * 4 + 3], ap);
        }
        if (j == 0) ap0 = ap;
        else if (j == 1) ap1 = ap;
        else if (j == 2) ap2 = ap;
        else ap3 = ap;
    }

    //=========== combine & store (one lane per row) ===========
    if (lane < 32) {
        const float am = 0.25f * (ap0 + ap1 + ap2 + ap3);
        float* __restrict__ o = out + (long long)row * 5;
        o[0] = value + ashoot;
        o[1] = value + ap0 - am;
        o[2] = value + ap1 - am;
        o[3] = value + ap2 - am;
        o[4] = value + ap3 - am;
    }
}

//======================= VALU fallback (known-passing) =======================
__global__ __launch_bounds__(256)
void dueling_fwd_valu(const float* __restrict__ state, const float* __restrict__ emb,
                      const float* __restrict__ wd1, const float* __restrict__ bd1,
                      const float* __restrict__ wd2, const float* __restrict__ bd2,
                      const float* __restrict__ wt1, const float* __restrict__ bt1,
                      const float* __restrict__ wt2, const float* __restrict__ bt2,
                      const float* __restrict__ wv1, const float* __restrict__ bv1,
                      const float* __restrict__ wv2, const float* __restrict__ bv2,
                      const float* __restrict__ wv3, const float* __restrict__ bv3,
                      const float* __restrict__ ws1, const float* __restrict__ bs1,
                      const float* __restrict__ ws2, const float* __restrict__ bs2,
                      const float* __restrict__ wp1, const float* __restrict__ bp1,
                      const float* __restrict__ wp2, const float* __restrict__ bp2,
                      const float* __restrict__ wp3, const float* __restrict__ bp3,
                      float* __restrict__ out, int nrows) {
    const int row = blockIdx.x * 256 + threadIdx.x;
    if (row >= nrows) return;
    const float* __restrict__ s = state + (long long)row * 78;
    float def_pooled[32];
#pragma unroll
    for (int n = 0; n < 32; ++n) def_pooled[n] = 0.0f;
#pragma unroll 1
    for (int p = 0; p < 5; ++p) {
        const float f0 = s[23 + 2 * p], f1 = s[24 + 2 * p], f2 = s[43 + 2 * p], f3 = s[44 + 2 * p];
        float h1[32];
#pragma unroll
        for (int n = 0; n < 32; ++n) {
            float a = bd1[n];
            a = fmaf(f0, wd1[n], a); a = fmaf(f1, wd1[32 + n], a);
            a = fmaf(f2, wd1[64 + n], a); a = fmaf(f3, wd1[96 + n], a);
            h1[n] = fmaxf(a, 0.0f);
        }
        float a2[32];
#pragma unroll
        for (int n = 0; n < 32; ++n) a2[n] = bd2[n];
#pragma unroll
        for (int k = 0; k < 32; ++k) {
            const float hk = h1[k];
#pragma unroll
            for (int n = 0; n < 32; ++n) a2[n] = fmaf(hk, wd2[k * 32 + n], a2[n]);
        }
#pragma unroll
        for (int n = 0; n < 32; ++n) def_pooled[n] += fmaxf(a2[n], 0.0f);
    }
    float base[53];
#pragma unroll
    for (int i = 0; i < 11; ++i) base[i] = s[i];
    base[11] = s[41]; base[12] = s[42];
    {
        int pid0 = (int)s[73];
        pid0 = pid0 < 0 ? 0 : (pid0 > 449 ? 449 : pid0);
        const float4 e0 = *(const float4*)(emb + pid0 * 8);
        const float4 e1 = *(const float4*)(emb + pid0 * 8 + 4);
        base[13] = e0.x; base[14] = e0.y; base[15] = e0.z; base[16] = e0.w;
        base[17] = e1.x; base[18] = e1.y; base[19] = e1.z; base[20] = e1.w;
    }
#pragma unroll
    for (int n = 0; n < 32; ++n) base[21 + n] = def_pooled[n] * 0.2f;
    float a_shoot;
    {
        float t[32];
#pragma unroll
        for (int n = 0; n < 32; ++n) t[n] = bs1[n];
#pragma unroll
        for (int k = 0; k < 53; ++k) {
            const float xk = base[k];
#pragma unroll
            for (int n = 0; n < 32; ++n) t[n] = fmaf(xk, ws1[k * 32 + n], t[n]);
        }
        a_shoot = bs2[0];
#pragma unroll
        for (int k = 0; k < 32; ++k) a_shoot = fmaf(fmaxf(t[k], 0.0f), ws2[k], a_shoot);
    }
    float value;
    {
        float h32[32];
#pragma unroll
        for (int n = 0; n < 32; ++n) h32[n] = bv2[n];
#pragma unroll
        for (int half = 0; half < 2; ++half) {
            float hh[32];
#pragma unroll
            for (int n = 0; n < 32; ++n) hh[n] = bv1[half * 32 + n];
#pragma unroll
            for (int k = 0; k < 53; ++k) {
                const float xk = base[k];
#pragma unroll
                for (int n = 0; n < 32; ++n) hh[n] = fmaf(xk, wv1[k * 64 + half * 32 + n], hh[n]);
            }
#pragma unroll
            for (int k = 0; k < 32; ++k) {
                const float xk = fmaxf(hh[k], 0.0f);
#pragma unroll
                for (int n = 0; n < 32; ++n) h32[n] = fmaf(xk, wv2[(half * 32 + k) * 32 + n], h32[n]);
            }
        }
        value = bv3[0];
#pragma unroll
        for (int k = 0; k < 32; ++k) value = fmaf(fmaxf(h32[k], 0.0f), wv3[k], value);
    }
    float pb[64];
#pragma unroll
    for (int n = 0; n < 64; ++n) pb[n] = bp1[n];
#pragma unroll
    for (int k = 0; k < 53; ++k) {
        const float xk = base[k];
#pragma unroll
        for (int n = 0; n < 64; ++n) pb[n] = fmaf(xk, wp1[(32 + k) * 64 + n], pb[n]);
    }
    float ap0 = 0.f, ap1 = 0.f, ap2 = 0.f, ap3 = 0.f;
#pragma unroll 1
    for (int j = 0; j < 4; ++j) {
        float t1[32];
        {
            float tf[18];
            tf[0] = s[33 + 2 * j]; tf[1] = s[34 + 2 * j];
            tf[2] = s[53 + 2 * j]; tf[3] = s[54 + 2 * j];
            tf[4] = s[11 + j]; tf[5] = s[15 + j]; tf[6] = s[19 + j];
            tf[7] = s[61 + j]; tf[8] = s[65 + j]; tf[9] = s[69 + j];
            int pid = (int)s[74 + j];
            pid = pid < 0 ? 0 : (pid > 449 ? 449 : pid);
            const float4 e0 = *(const float4*)(emb + pid * 8);
            const float4 e1 = *(const float4*)(emb + pid * 8 + 4);
            tf[10] = e0.x; tf[11] = e0.y; tf[12] = e0.z; tf[13] = e0.w;
            tf[14] = e1.x; tf[15] = e1.y; tf[16] = e1.z; tf[17] = e1.w;
#pragma unroll
            for (int n = 0; n < 32; ++n) t1[n] = bt1[n];
#pragma unroll
            for (int k = 0; k < 18; ++k) {
                const float xk = tf[k];
#pragma unroll
                for (int n = 0; n < 32; ++n) t1[n] = fmaf(xk, wt1[k * 32 + n], t1[n]);
            }
        }
        float t2[32];
#pragma unroll
        for (int n = 0; n < 32; ++n) t2[n] = bt2[n];
#pragma unroll
        for (int k = 0; k < 32; ++k) {
            const float xk = fmaxf(t1[k], 0.0f);
#pragma unroll
            for (int n = 0; n < 32; ++n) t2[n] = fmaf(xk, wt2[k * 32 + n], t2[n]);
        }
#pragma unroll
        for (int n = 0; n < 32; ++n) t2[n] = fmaxf(t2[n], 0.0f);
        float p2[16];
#pragma unroll
        for (int n = 0; n < 16; ++n) p2[n] = bp2[n];
#pragma unroll
        for (int half = 0; half < 2; ++half) {
            float phh[32];
#pragma unroll
            for (int n = 0; n < 32; ++n) phh[n] = pb[half * 32 + n];
#pragma unroll
            for (int k = 0; k < 32; ++k) {
                const float xk = t2[k];
#pragma unroll
                for (int n = 0; n < 32; ++n) phh[n] = fmaf(xk, wp1[k * 64 + half * 32 + n], phh[n]);
            }
#pragma unroll
            for (int k = 0; k < 32; ++k) {
                const float xk = fmaxf(phh[k], 0.0f);
#pragma unroll
                for (int n = 0; n < 16; ++n) p2[n] = fmaf(xk, wp2[(half * 32 + k) * 16 + n], p2[n]);
            }
        }
        float a = bp3[0];
#pragma unroll
        for (int k = 0; k < 16; ++k) a = fmaf(fmaxf(p2[k], 0.0f), wp3[k], a);
        if (j == 0) ap0 = a; else if (j == 1) ap1 = a; else if (j == 2) ap2 = a; else ap3 = a;
    }
    const float am = 0.25f * (ap0 + ap1 + ap2 + ap3);
    float* __restrict__ o = out + (long long)row * 5;
    o[0] = value + a_shoot;
    o[1] = value + ap0 - am;
    o[2] = value + ap1 - am;
    o[3] = value + ap2 - am;
    o[4] = value + ap3 - am;
}

extern "C" void kernel_launch(void* const* d_in, const int* in_sizes, int n_in,
                              void* d_out, int out_size, void* d_ws, size_t ws_size,
                              hipStream_t stream) {
    const float* state = (const float*)d_in[0];
    const float* emb   = (const float*)d_in[1];
    const float* wd1 = (const float*)d_in[2];  const float* bd1 = (const float*)d_in[3];
    const float* wd2 = (const float*)d_in[4];  const float* bd2 = (const float*)d_in[5];
    const float* wt1 = (const float*)d_in[6];  const float* bt1 = (const float*)d_in[7];
    const float* wt2 = (const float*)d_in[8];  const float* bt2 = (const float*)d_in[9];
    const float* wv1 = (const float*)d_in[10]; const float* bv1 = (const float*)d_in[11];
    const float* wv2 = (const float*)d_in[12]; const float* bv2 = (const float*)d_in[13];
    const float* wv3 = (const float*)d_in[14]; const float* bv3 = (const float*)d_in[15];
    const float* ws1 = (const float*)d_in[16]; const float* bs1 = (const float*)d_in[17];
    const float* ws2 = (const float*)d_in[18]; const float* bs2 = (const float*)d_in[19];
    const float* wp1 = (const float*)d_in[20]; const float* bp1 = (const float*)d_in[21];
    const float* wp2 = (const float*)d_in[22]; const float* bp2 = (const float*)d_in[23];
    const float* wp3 = (const float*)d_in[24]; const float* bp3 = (const float*)d_in[25];

    const int nrows = in_sizes[0] / 78;

    if (ws_size < (size_t)WS_BYTES || (nrows & 511) != 0) {
        const int blocks = (nrows + 255) / 256;
        dueling_fwd_valu<<<blocks, 256, 0, stream>>>(
            state, emb, wd1, bd1, wd2, bd2, wt1, bt1, wt2, bt2,
            wv1, bv1, wv2, bv2, wv3, bv3, ws1, bs1, ws2, bs2,
            wp1, bp1, wp2, bp2, wp3, bp3, (float*)d_out, nrows);
        return;
    }

    prep_weights<<<36, 64, 0, stream>>>(wd2, wt1, wt2, wp1, wp2, wv1, wv2, ws1,
                                        (uint4*)d_ws);
    dueling_mfma<<<nrows / 512, THREADS, 0, stream>>>(
        state, emb, wd1, bd1, bd2, bt1, bt2, bv1, bv2, wv3, bv3,
        bs1, ws2, bs2, bp1, bp2, wp3,
        (const uint4*)d_ws, (float*)d_out, nrows);
}

// Round 15
// 126.164 us; speedup vs baseline: 2.1093x; 2.1093x over previous
//
#include <hip/hip_runtime.h>
#include <hip/hip_bf16.h>

#define THREADS 256   // 4 waves/block, 36864 B LDS -> HW can pack 2-4 blocks/CU

typedef short bf16x8 __attribute__((ext_vector_type(8)));
typedef float f32x4 __attribute__((ext_vector_type(4)));

union FragU { unsigned u[4]; bf16x8 v; };

// ---- split f32x8 into bf16 hi/lo fragments (hi=rne(x), lo=rne(x-hi)) ----
__device__ __forceinline__ void split8(const float* x, FragU& hi, FragU& lo) {
#pragma unroll
    for (int i = 0; i < 4; ++i) {
        float a = x[2 * i], b = x[2 * i + 1];
        __hip_bfloat162 h2 = __float22bfloat162_rn(make_float2(a, b));
        float ra = __bfloat162float(h2.x), rb = __bfloat162float(h2.y);
        __hip_bfloat162 l2 = __float22bfloat162_rn(make_float2(a - ra, b - rb));
        unsigned hu, lu;
        __builtin_memcpy(&hu, &h2, 4);
        __builtin_memcpy(&lu, &l2, 4);
        hi.u[i] = hu; lo.u[i] = lu;
    }
}

// ---- 3-product split-bf16 MFMA: D += (Ah+Al)(Bh+Bl) - Al*Bl ----
__device__ __forceinline__ f32x4 mm3(const FragU& ah, const FragU& al,
                                     const FragU& bh, const FragU& bl, f32x4 acc) {
    acc = __builtin_amdgcn_mfma_f32_16x16x32_bf16(al.v, bh.v, acc, 0, 0, 0);
    acc = __builtin_amdgcn_mfma_f32_16x16x32_bf16(ah.v, bl.v, acc, 0, 0, 0);
    acc = __builtin_amdgcn_mfma_f32_16x16x32_bf16(ah.v, bh.v, acc, 0, 0, 0);
    return acc;
}

__device__ __forceinline__ void load_pair(const uint4* __restrict__ ws, int pair, int lane,
                                          FragU& hi, FragU& lo) {
    uint4 a = ws[pair * 128 + lane];
    uint4 b = ws[pair * 128 + 64 + lane];
    hi.u[0] = a.x; hi.u[1] = a.y; hi.u[2] = a.z; hi.u[3] = a.w;
    lo.u[0] = b.x; lo.u[1] = b.y; lo.u[2] = b.z; lo.u[3] = b.w;
}

// A frag from LDS row-major (stride dwords): row=lane&15 (+m*16), k=(lane>>4)*8+j
__device__ __forceinline__ void buildA(const float* buf, int stride, int m, int kf, int lane,
                                       FragU& hi, FragU& lo) {
    const float* p = buf + (m * 16 + (lane & 15)) * stride + kf * 32 + ((lane >> 4) * 8);
    float x[8];
    *reinterpret_cast<float4*>(&x[0]) = *reinterpret_cast<const float4*>(p);
    *reinterpret_cast<float4*>(&x[4]) = *reinterpret_cast<const float4*>(p + 4);
    split8(x, hi, lo);
}

// C frag to LDS row-major: col=lane&15 (+nf*16), row=(lane>>4)*4+q (+m*16)
__device__ __forceinline__ void storeC(float* buf, int stride, int m, int nf, int lane, f32x4 c) {
    float* p = buf + (((lane >> 4) * 4) + m * 16) * stride + nf * 16 + (lane & 15);
    p[0] = c[0]; p[stride] = c[1]; p[2 * stride] = c[2]; p[3 * stride] = c[3];
}

// pair table: pair = base + kf*NF + nf   (same as R6-R14, prep unchanged)
#define PB_D2  0
#define PB_T1  2
#define PB_T2  4
#define PB_P1T 6
#define PB_P1B 10
#define PB_P2  18
#define PB_V1  20
#define PB_V2  28
#define PB_S1  32
#define WS_BYTES (36 * 2048)

__global__ __launch_bounds__(64)
void prep_weights(const float* __restrict__ wd2, const float* __restrict__ wt1,
                  const float* __restrict__ wt2, const float* __restrict__ wp1,
                  const float* __restrict__ wp2, const float* __restrict__ wv1,
                  const float* __restrict__ wv2, const float* __restrict__ ws1,
                  uint4* __restrict__ wsout) {
    const int pair = blockIdx.x;
    const int lane = threadIdx.x;
    const int base_[10]  = {0, 2, 4, 6, 10, 18, 20, 28, 32, 36};
    const int kreal_[9]  = {32, 18, 32, 32, 53, 64, 53, 64, 53};
    const int n_[9]      = {32, 32, 32, 64, 64, 16, 64, 32, 32};
    const int nfc_[9]    = {2, 2, 2, 4, 4, 1, 4, 2, 2};
    const int roff_[9]   = {0, 0, 0, 0, 32, 0, 0, 0, 0};
    int g = 0;
    while (g < 8 && pair >= base_[g + 1]) ++g;
    const int local = pair - base_[g];
    const int kf = local / nfc_[g];
    const int nfi = local % nfc_[g];
    const float* W = (g == 0) ? wd2 : (g == 1) ? wt1 : (g == 2) ? wt2 :
                     (g == 3 || g == 4) ? wp1 : (g == 5) ? wp2 :
                     (g == 6) ? wv1 : (g == 7) ? wv2 : ws1;
    const int N = n_[g];
    float x[8];
#pragma unroll
    for (int j = 0; j < 8; ++j) {
        const int k = kf * 32 + (lane >> 4) * 8 + j;
        const int n = nfi * 16 + (lane & 15);
        x[j] = (k < kreal_[g]) ? W[(roff_[g] + k) * N + n] : 0.0f;
    }
    FragU hi, lo;
    split8(x, hi, lo);
    wsout[pair * 128 + lane]      = make_uint4(hi.u[0], hi.u[1], hi.u[2], hi.u[3]);
    wsout[pair * 128 + 64 + lane] = make_uint4(lo.u[0], lo.u[1], lo.u[2], lo.u[3]);
}

#define SB 68
#define SS 36
// 32 rows/wave (m=2), R11 sequential structure. Per-wave LDS region = 2304 f:
//   phase 1: BASE[32][68] = 2176 f (cols 0..52 data, 53..63 zero K-pad)
//   phase 2: BUFA[32][36] (0..1151) + BUFB[32][36] (1152..2303), ALIASED on BASE
// 4 waves x 9216 B = 36864 B/block. R14 law: default VGPR cap = 65536/THREADS
// (compiler assumes 2 blocks/CU) -> 256-thr = 256 cap, our ~120 fits free.
// R8: 72KB blocks never pair; hypothesis: <=64KB blocks do -> 2-4 blocks/CU.
#define WAVE_F 2304

__global__ __launch_bounds__(THREADS)   // plain: min-waves attr triggers demotion (R3/R4/R10)
void dueling_mfma(const float* __restrict__ state, const float* __restrict__ emb,
                  const float* __restrict__ wd1, const float* __restrict__ bd1,
                  const float* __restrict__ bd2, const float* __restrict__ bt1,
                  const float* __restrict__ bt2, const float* __restrict__ bv1,
                  const float* __restrict__ bv2, const float* __restrict__ wv3,
                  const float* __restrict__ bv3, const float* __restrict__ bs1,
                  const float* __restrict__ ws2, const float* __restrict__ bs2,
                  const float* __restrict__ bp1, const float* __restrict__ bp2,
                  const float* __restrict__ wp3,
                  const uint4* __restrict__ ws, float* __restrict__ out, int nrows) {
    __shared__ float smem[4 * WAVE_F];    // 36864 B
    const int lane = threadIdx.x & 63;
    const int wave = threadIdx.x >> 6;    // 0..3
    const int r    = lane & 31;           // row within wave tile
    const int sub  = lane >> 5;           // sublane for split staging
    const int row  = blockIdx.x * 128 + wave * 32 + r;
    const float* __restrict__ s = state + (long long)row * 78;

    float* BASE = smem + wave * WAVE_F;
    float* BUFA = BASE;                   // phase-2 alias (BASE dead after X hoist)
    float* BUFB = BASE + 32 * SS;         // +1152 floats
    float* HST  = BASE + 24;              // defender h staging (cols 24..55)
    const int c16 = lane & 15;

    // zero whole wave region: 2304 f = 9 x (64 lanes x float4)
#pragma unroll
    for (int i = 0; i < 9; ++i)
        *reinterpret_cast<float4*>(BASE + i * 256 + lane * 4) = make_float4(0.f, 0.f, 0.f, 0.f);

    //=========== per-lane features -> BASE cols 0..20 (lanes 0..31, one per row) ===========
    if (lane < 32) {
        int pid0 = (int)s[73];
        pid0 = pid0 < 0 ? 0 : (pid0 > 449 ? 449 : pid0);
        const float4 e0 = *(const float4*)(emb + pid0 * 8);
        const float4 e1 = *(const float4*)(emb + pid0 * 8 + 4);
        float* bp = BASE + r * SB;
        *reinterpret_cast<float4*>(bp +  0) = make_float4(s[0], s[1], s[2], s[3]);
        *reinterpret_cast<float4*>(bp +  4) = make_float4(s[4], s[5], s[6], s[7]);
        *reinterpret_cast<float4*>(bp +  8) = make_float4(s[8], s[9], s[10], s[41]);
        *reinterpret_cast<float4*>(bp + 12) = make_float4(s[42], e0.x, e0.y, e0.z);
        *reinterpret_cast<float4*>(bp + 16) = make_float4(e0.w, e1.x, e1.y, e1.z);
        bp[20] = e1.w;
    }

    //=========== defender head: d1 split across sublanes (branchless), d2 MFMA ===========
    float pool[2][2][4];
#pragma unroll
    for (int m = 0; m < 2; ++m)
#pragma unroll
        for (int nf = 0; nf < 2; ++nf)
#pragma unroll
            for (int q = 0; q < 4; ++q) pool[m][nf][q] = 0.0f;

#pragma unroll 1
    for (int p = 0; p < 5; ++p) {
        const float f0 = s[23 + 2 * p], f1 = s[24 + 2 * p];
        const float f2 = s[43 + 2 * p], f3 = s[44 + 2 * p];
#pragma unroll
        for (int i2 = 0; i2 < 4; ++i2) {
            const int i = sub * 4 + i2;          // sublane 0: n 0..15, sublane 1: n 16..31
            const float4 b4 = *(const float4*)(bd1 + i * 4);
            const float4 w0 = *(const float4*)(wd1 + 0 * 32 + i * 4);
            const float4 w1 = *(const float4*)(wd1 + 1 * 32 + i * 4);
            const float4 w2 = *(const float4*)(wd1 + 2 * 32 + i * 4);
            const float4 w3 = *(const float4*)(wd1 + 3 * 32 + i * 4);
            float4 hv;
            hv.x = fmaxf(fmaf(f0, w0.x, fmaf(f1, w1.x, fmaf(f2, w2.x, fmaf(f3, w3.x, b4.x)))), 0.f);
            hv.y = fmaxf(fmaf(f0, w0.y, fmaf(f1, w1.y, fmaf(f2, w2.y, fmaf(f3, w3.y, b4.y)))), 0.f);
            hv.z = fmaxf(fmaf(f0, w0.z, fmaf(f1, w1.z, fmaf(f2, w2.z, fmaf(f3, w3.z, b4.z)))), 0.f);
            hv.w = fmaxf(fmaf(f0, w0.w, fmaf(f1, w1.w, fmaf(f2, w2.w, fmaf(f3, w3.w, b4.w)))), 0.f);
            *reinterpret_cast<float4*>(BASE + r * SB + 24 + i * 4) = hv;
        }

        FragU ah[2], al[2];
#pragma unroll
        for (int m = 0; m < 2; ++m) buildA(HST, SB, m, 0, lane, ah[m], al[m]);
#pragma unroll
        for (int nf = 0; nf < 2; ++nf) {
            FragU bh, bl; load_pair(ws, PB_D2 + nf, lane, bh, bl);
            const float bias = bd2[nf * 16 + c16];
#pragma unroll
            for (int m = 0; m < 2; ++m) {
                f32x4 acc = {bias, bias, bias, bias};
                acc = mm3(ah[m], al[m], bh, bl, acc);
#pragma unroll
                for (int q = 0; q < 4; ++q) pool[m][nf][q] += fmaxf(acc[q], 0.0f);
            }
        }
    }
    // re-zero K-pad cols 53..55 dirtied by h staging (both sublanes write 0: benign)
    BASE[r * SB + 53] = 0.0f;
    BASE[r * SB + 54] = 0.0f;
    BASE[r * SB + 55] = 0.0f;
    // pooled/5 -> BASE cols 21..52 (C-layout writes, rows 0..31)
#pragma unroll
    for (int m = 0; m < 2; ++m)
#pragma unroll
        for (int nf = 0; nf < 2; ++nf)
#pragma unroll
            for (int q = 0; q < 4; ++q)
                BASE[((lane >> 4) * 4 + q + m * 16) * SB + 21 + nf * 16 + c16] =
                    pool[m][nf][q] * 0.2f;

    //=========== HOIST: BASE A-fragments (4 pairs = 32 VGPR; BASE LDS dead after) ===========
    FragU Xh[2][2], Xl[2][2];
#pragma unroll
    for (int m = 0; m < 2; ++m)
#pragma unroll
        for (int kf = 0; kf < 2; ++kf)
            buildA(BASE, SB, m, kf, lane, Xh[m][kf], Xl[m][kf]);

    //=========== value head ===========
    float v2acc[2][2][4];
#pragma unroll
    for (int m = 0; m < 2; ++m)
#pragma unroll
        for (int nf = 0; nf < 2; ++nf) {
            const float b = bv2[nf * 16 + c16];
#pragma unroll
            for (int q = 0; q < 4; ++q) v2acc[m][nf][q] = b;
        }
#pragma unroll 1
    for (int half = 0; half < 2; ++half) {
#pragma unroll
        for (int nfl = 0; nfl < 2; ++nfl) {
            const int ng = half * 2 + nfl;
            FragU b0h, b0l, b1h, b1l;
            load_pair(ws, PB_V1 + ng, lane, b0h, b0l);
            load_pair(ws, PB_V1 + 4 + ng, lane, b1h, b1l);
            const float bias = bv1[ng * 16 + c16];
#pragma unroll
            for (int m = 0; m < 2; ++m) {
                f32x4 acc = {bias, bias, bias, bias};
                acc = mm3(Xh[m][0], Xl[m][0], b0h, b0l, acc);
                acc = mm3(Xh[m][1], Xl[m][1], b1h, b1l, acc);
#pragma unroll
                for (int q = 0; q < 4; ++q) acc[q] = fmaxf(acc[q], 0.0f);
                storeC(BUFA, SS, m, nfl, lane, acc);
            }
        }
        FragU ah[2], al[2];
#pragma unroll
        for (int m = 0; m < 2; ++m) buildA(BUFA, SS, m, 0, lane, ah[m], al[m]);
#pragma unroll
        for (int nf = 0; nf < 2; ++nf) {
            FragU bh, bl; load_pair(ws, PB_V2 + half * 2 + nf, lane, bh, bl);
#pragma unroll
            for (int m = 0; m < 2; ++m) {
                f32x4 acc = {v2acc[m][nf][0], v2acc[m][nf][1], v2acc[m][nf][2], v2acc[m][nf][3]};
                acc = mm3(ah[m], al[m], bh, bl, acc);
#pragma unroll
                for (int q = 0; q < 4; ++q) v2acc[m][nf][q] = acc[q];
            }
        }
    }
#pragma unroll
    for (int m = 0; m < 2; ++m)
#pragma unroll
        for (int nf = 0; nf < 2; ++nf) {
            f32x4 rr = {fmaxf(v2acc[m][nf][0], 0.f), fmaxf(v2acc[m][nf][1], 0.f),
                        fmaxf(v2acc[m][nf][2], 0.f), fmaxf(v2acc[m][nf][3], 0.f)};
            storeC(BUFA, SS, m, nf, lane, rr);
        }
    float value = bv3[0];
#pragma unroll
    for (int c4 = 0; c4 < 8; ++c4) {
        float4 v = *reinterpret_cast<const float4*>(BUFA + r * SS + c4 * 4);
        value = fmaf(v.x, wv3[c4 * 4], value);
        value = fmaf(v.y, wv3[c4 * 4 + 1], value);
        value = fmaf(v.z, wv3[c4 * 4 + 2], value);
        value = fmaf(v.w, wv3[c4 * 4 + 3], value);
    }

    //=========== shoot head (uses hoisted X frags) ===========
#pragma unroll
    for (int nf = 0; nf < 2; ++nf) {
        FragU b0h, b0l, b1h, b1l;
        load_pair(ws, PB_S1 + nf, lane, b0h, b0l);
        load_pair(ws, PB_S1 + 2 + nf, lane, b1h, b1l);
        const float bias = bs1[nf * 16 + c16];
#pragma unroll
        for (int m = 0; m < 2; ++m) {
            f32x4 acc = {bias, bias, bias, bias};
            acc = mm3(Xh[m][0], Xl[m][0], b0h, b0l, acc);
            acc = mm3(Xh[m][1], Xl[m][1], b1h, b1l, acc);
#pragma unroll
            for (int q = 0; q < 4; ++q) acc[q] = fmaxf(acc[q], 0.0f);
            storeC(BUFA, SS, m, nf, lane, acc);
        }
    }
    float ashoot = bs2[0];
#pragma unroll
    for (int c4 = 0; c4 < 8; ++c4) {
        float4 v = *reinterpret_cast<const float4*>(BUFA + r * SS + c4 * 4);
        ashoot = fmaf(v.x, ws2[c4 * 4], ashoot);
        ashoot = fmaf(v.y, ws2[c4 * 4 + 1], ashoot);
        ashoot = fmaf(v.z, ws2[c4 * 4 + 2], ashoot);
        ashoot = fmaf(v.w, ws2[c4 * 4 + 3], ashoot);
    }

    //=========== teammates (sequential, R11 structure) ===========
    float ap0 = 0.f, ap1 = 0.f, ap2 = 0.f, ap3 = 0.f;
#pragma unroll 1
    for (int j = 0; j < 4; ++j) {
        if (lane < 32) {
            int pid = (int)s[74 + j];
            pid = pid < 0 ? 0 : (pid > 449 ? 449 : pid);
            const float4 e0 = *(const float4*)(emb + pid * 8);
            const float4 e1 = *(const float4*)(emb + pid * 8 + 4);
            float* tp = BUFA + r * SS;
            *reinterpret_cast<float4*>(tp +  0) =
                make_float4(s[33 + 2 * j], s[34 + 2 * j], s[53 + 2 * j], s[54 + 2 * j]);
            *reinterpret_cast<float4*>(tp +  4) =
                make_float4(s[11 + j], s[15 + j], s[19 + j], s[61 + j]);
            *reinterpret_cast<float4*>(tp +  8) = make_float4(s[65 + j], s[69 + j], e0.x, e0.y);
            *reinterpret_cast<float4*>(tp + 12) = make_float4(e0.z, e0.w, e1.x, e1.y);
            *reinterpret_cast<float4*>(tp + 16) = make_float4(e1.z, e1.w, 0.f, 0.f);
            *reinterpret_cast<float4*>(tp + 20) = make_float4(0.f, 0.f, 0.f, 0.f);
            *reinterpret_cast<float4*>(tp + 24) = make_float4(0.f, 0.f, 0.f, 0.f);
            *reinterpret_cast<float4*>(tp + 28) = make_float4(0.f, 0.f, 0.f, 0.f);
        }
        // t1: BUFA -> BUFB
        {
            FragU ah[2], al[2];
#pragma unroll
            for (int m = 0; m < 2; ++m) buildA(BUFA, SS, m, 0, lane, ah[m], al[m]);
#pragma unroll
            for (int nf = 0; nf < 2; ++nf) {
                FragU bh, bl; load_pair(ws, PB_T1 + nf, lane, bh, bl);
                const float bias = bt1[nf * 16 + c16];
#pragma unroll
                for (int m = 0; m < 2; ++m) {
                    f32x4 acc = {bias, bias, bias, bias};
                    acc = mm3(ah[m], al[m], bh, bl, acc);
#pragma unroll
                    for (int q = 0; q < 4; ++q) acc[q] = fmaxf(acc[q], 0.0f);
                    storeC(BUFB, SS, m, nf, lane, acc);
                }
            }
        }
        // t2: BUFB -> BUFA
        {
            FragU ah[2], al[2];
#pragma unroll
            for (int m = 0; m < 2; ++m) buildA(BUFB, SS, m, 0, lane, ah[m], al[m]);
#pragma unroll
            for (int nf = 0; nf < 2; ++nf) {
                FragU bh, bl; load_pair(ws, PB_T2 + nf, lane, bh, bl);
                const float bias = bt2[nf * 16 + c16];
#pragma unroll
                for (int m = 0; m < 2; ++m) {
                    f32x4 acc = {bias, bias, bias, bias};
                    acc = mm3(ah[m], al[m], bh, bl, acc);
#pragma unroll
                    for (int q = 0; q < 4; ++q) acc[q] = fmaxf(acc[q], 0.0f);
                    storeC(BUFA, SS, m, nf, lane, acc);
                }
            }
        }
        // hoist t2 frags for p1t (reused across half & nfl)
        FragU th[2], tl2[2];
#pragma unroll
        for (int m = 0; m < 2; ++m) buildA(BUFA, SS, m, 0, lane, th[m], tl2[m]);

        float p2acc[2][4];
        {
            const float bq = bp2[c16];
#pragma unroll
            for (int m = 0; m < 2; ++m)
#pragma unroll
                for (int q = 0; q < 4; ++q) p2acc[m][q] = bq;
        }
#pragma unroll 1
        for (int half = 0; half < 2; ++half) {
#pragma unroll
            for (int nfl = 0; nfl < 2; ++nfl) {
                const int ng = half * 2 + nfl;
                FragU bth, btl, b0h, b0l, b1h, b1l;
                load_pair(ws, PB_P1T + ng, lane, bth, btl);
                load_pair(ws, PB_P1B + ng, lane, b0h, b0l);
                load_pair(ws, PB_P1B + 4 + ng, lane, b1h, b1l);
                const float bias = bp1[ng * 16 + c16];
#pragma unroll
                for (int m = 0; m < 2; ++m) {
                    f32x4 acc = {bias, bias, bias, bias};
                    acc = mm3(th[m], tl2[m], bth, btl, acc);
                    acc = mm3(Xh[m][0], Xl[m][0], b0h, b0l, acc);
                    acc = mm3(Xh[m][1], Xl[m][1], b1h, b1l, acc);
#pragma unroll
                    for (int q = 0; q < 4; ++q) acc[q] = fmaxf(acc[q], 0.0f);
                    storeC(BUFB, SS, m, nfl, lane, acc);
                }
            }
            FragU bh, bl; load_pair(ws, PB_P2 + half, lane, bh, bl);
#pragma unroll
            for (int m = 0; m < 2; ++m) {
                FragU ah, al; buildA(BUFB, SS, m, 0, lane, ah, al);
                f32x4 acc = {p2acc[m][0], p2acc[m][1], p2acc[m][2], p2acc[m][3]};
                acc = mm3(ah, al, bh, bl, acc);
#pragma unroll
                for (int q = 0; q < 4; ++q) p2acc[m][q] = acc[q];
            }
        }
#pragma unroll
        for (int m = 0; m < 2; ++m) {
            f32x4 rr = {fmaxf(p2acc[m][0], 0.f), fmaxf(p2acc[m][1], 0.f),
                        fmaxf(p2acc[m][2], 0.f), fmaxf(p2acc[m][3], 0.f)};
            storeC(BUFB, SS, m, 0, lane, rr);
        }
        float ap = 0.0f;
#pragma unroll
        for (int c4 = 0; c4 < 4; ++c4) {
            float4 v = *reinterpret_cast<const float4*>(BUFB + r * SS + c4 * 4);
            ap = fmaf(v.x, wp3[c4 * 4], ap);
            ap = fmaf(v.y, wp3[c4 * 4 + 1], ap);
            ap = fmaf(v.z, wp3[c4 * 4 + 2], ap);
            ap = fmaf(v.w, wp3[c4 * 4 + 3], ap);
        }
        if (j == 0) ap0 = ap;
        else if (j == 1) ap1 = ap;
        else if (j == 2) ap2 = ap;
        else ap3 = ap;
    }

    //=========== combine & store (one lane per row) ===========
    if (lane < 32) {
        const float am = 0.25f * (ap0 + ap1 + ap2 + ap3);
        float* __restrict__ o = out + (long long)row * 5;
        o[0] = value + ashoot;
        o[1] = value + ap0 - am;
        o[2] = value + ap1 - am;
        o[3] = value + ap2 - am;
        o[4] = value + ap3 - am;
    }
}

//======================= VALU fallback (known-passing) =======================
__global__ __launch_bounds__(256)
void dueling_fwd_valu(const float* __restrict__ state, const float* __restrict__ emb,
                      const float* __restrict__ wd1, const float* __restrict__ bd1,
                      const float* __restrict__ wd2, const float* __restrict__ bd2,
                      const float* __restrict__ wt1, const float* __restrict__ bt1,
                      const float* __restrict__ wt2, const float* __restrict__ bt2,
                      const float* __restrict__ wv1, const float* __restrict__ bv1,
                      const float* __restrict__ wv2, const float* __restrict__ bv2,
                      const float* __restrict__ wv3, const float* __restrict__ bv3,
                      const float* __restrict__ ws1, const float* __restrict__ bs1,
                      const float* __restrict__ ws2, const float* __restrict__ bs2,
                      const float* __restrict__ wp1, const float* __restrict__ bp1,
                      const float* __restrict__ wp2, const float* __restrict__ bp2,
                      const float* __restrict__ wp3, const float* __restrict__ bp3,
                      float* __restrict__ out, int nrows) {
    const int row = blockIdx.x * 256 + threadIdx.x;
    if (row >= nrows) return;
    const float* __restrict__ s = state + (long long)row * 78;
    float def_pooled[32];
#pragma unroll
    for (int n = 0; n < 32; ++n) def_pooled[n] = 0.0f;
#pragma unroll 1
    for (int p = 0; p < 5; ++p) {
        const float f0 = s[23 + 2 * p], f1 = s[24 + 2 * p], f2 = s[43 + 2 * p], f3 = s[44 + 2 * p];
        float h1[32];
#pragma unroll
        for (int n = 0; n < 32; ++n) {
            float a = bd1[n];
            a = fmaf(f0, wd1[n], a); a = fmaf(f1, wd1[32 + n], a);
            a = fmaf(f2, wd1[64 + n], a); a = fmaf(f3, wd1[96 + n], a);
            h1[n] = fmaxf(a, 0.0f);
        }
        float a2[32];
#pragma unroll
        for (int n = 0; n < 32; ++n) a2[n] = bd2[n];
#pragma unroll
        for (int k = 0; k < 32; ++k) {
            const float hk = h1[k];
#pragma unroll
            for (int n = 0; n < 32; ++n) a2[n] = fmaf(hk, wd2[k * 32 + n], a2[n]);
        }
#pragma unroll
        for (int n = 0; n < 32; ++n) def_pooled[n] += fmaxf(a2[n], 0.0f);
    }
    float base[53];
#pragma unroll
    for (int i = 0; i < 11; ++i) base[i] = s[i];
    base[11] = s[41]; base[12] = s[42];
    {
        int pid0 = (int)s[73];
        pid0 = pid0 < 0 ? 0 : (pid0 > 449 ? 449 : pid0);
        const float4 e0 = *(const float4*)(emb + pid0 * 8);
        const float4 e1 = *(const float4*)(emb + pid0 * 8 + 4);
        base[13] = e0.x; base[14] = e0.y; base[15] = e0.z; base[16] = e0.w;
        base[17] = e1.x; base[18] = e1.y; base[19] = e1.z; base[20] = e1.w;
    }
#pragma unroll
    for (int n = 0; n < 32; ++n) base[21 + n] = def_pooled[n] * 0.2f;
    float a_shoot;
    {
        float t[32];
#pragma unroll
        for (int n = 0; n < 32; ++n) t[n] = bs1[n];
#pragma unroll
        for (int k = 0; k < 53; ++k) {
            const float xk = base[k];
#pragma unroll
            for (int n = 0; n < 32; ++n) t[n] = fmaf(xk, ws1[k * 32 + n], t[n]);
        }
        a_shoot = bs2[0];
#pragma unroll
        for (int k = 0; k < 32; ++k) a_shoot = fmaf(fmaxf(t[k], 0.0f), ws2[k], a_shoot);
    }
    float value;
    {
        float h32[32];
#pragma unroll
        for (int n = 0; n < 32; ++n) h32[n] = bv2[n];
#pragma unroll
        for (int half = 0; half < 2; ++half) {
            float hh[32];
#pragma unroll
            for (int n = 0; n < 32; ++n) hh[n] = bv1[half * 32 + n];
#pragma unroll
            for (int k = 0; k < 53; ++k) {
                const float xk = base[k];
#pragma unroll
                for (int n = 0; n < 32; ++n) hh[n] = fmaf(xk, wv1[k * 64 + half * 32 + n], hh[n]);
            }
#pragma unroll
            for (int k = 0; k < 32; ++k) {
                const float xk = fmaxf(hh[k], 0.0f);
#pragma unroll
                for (int n = 0; n < 32; ++n) h32[n] = fmaf(xk, wv2[(half * 32 + k) * 32 + n], h32[n]);
            }
        }
        value = bv3[0];
#pragma unroll
        for (int k = 0; k < 32; ++k) value = fmaf(fmaxf(h32[k], 0.0f), wv3[k], value);
    }
    float pb[64];
#pragma unroll
    for (int n = 0; n < 64; ++n) pb[n] = bp1[n];
#pragma unroll
    for (int k = 0; k < 53; ++k) {
        const float xk = base[k];
#pragma unroll
        for (int n = 0; n < 64; ++n) pb[n] = fmaf(xk, wp1[(32 + k) * 64 + n], pb[n]);
    }
    float ap0 = 0.f, ap1 = 0.f, ap2 = 0.f, ap3 = 0.f;
#pragma unroll 1
    for (int j = 0; j < 4; ++j) {
        float t1[32];
        {
            float tf[18];
            tf[0] = s[33 + 2 * j]; tf[1] = s[34 + 2 * j];
            tf[2] = s[53 + 2 * j]; tf[3] = s[54 + 2 * j];
            tf[4] = s[11 + j]; tf[5] = s[15 + j]; tf[6] = s[19 + j];
            tf[7] = s[61 + j]; tf[8] = s[65 + j]; tf[9] = s[69 + j];
            int pid = (int)s[74 + j];
            pid = pid < 0 ? 0 : (pid > 449 ? 449 : pid);
            const float4 e0 = *(const float4*)(emb + pid * 8);
            const float4 e1 = *(const float4*)(emb + pid * 8 + 4);
            tf[10] = e0.x; tf[11] = e0.y; tf[12] = e0.z; tf[13] = e0.w;
            tf[14] = e1.x; tf[15] = e1.y; tf[16] = e1.z; tf[17] = e1.w;
#pragma unroll
            for (int n = 0; n < 32; ++n) t1[n] = bt1[n];
#pragma unroll
            for (int k = 0; k < 18; ++k) {
                const float xk = tf[k];
#pragma unroll
                for (int n = 0; n < 32; ++n) t1[n] = fmaf(xk, wt1[k * 32 + n], t1[n]);
            }
        }
        float t2[32];
#pragma unroll
        for (int n = 0; n < 32; ++n) t2[n] = bt2[n];
#pragma unroll
        for (int k = 0; k < 32; ++k) {
            const float xk = fmaxf(t1[k], 0.0f);
#pragma unroll
            for (int n = 0; n < 32; ++n) t2[n] = fmaf(xk, wt2[k * 32 + n], t2[n]);
        }
#pragma unroll
        for (int n = 0; n < 32; ++n) t2[n] = fmaxf(t2[n], 0.0f);
        float p2[16];
#pragma unroll
        for (int n = 0; n < 16; ++n) p2[n] = bp2[n];
#pragma unroll
        for (int half = 0; half < 2; ++half) {
            float phh[32];
#pragma unroll
            for (int n = 0; n < 32; ++n) phh[n] = pb[half * 32 + n];
#pragma unroll
            for (int k = 0; k < 32; ++k) {
                const float xk = t2[k];
#pragma unroll
                for (int n = 0; n < 32; ++n) phh[n] = fmaf(xk, wp1[k * 64 + half * 32 + n], phh[n]);
            }
#pragma unroll
            for (int k = 0; k < 32; ++k) {
                const float xk = fmaxf(phh[k], 0.0f);
#pragma unroll
                for (int n = 0; n < 16; ++n) p2[n] = fmaf(xk, wp2[(half * 32 + k) * 16 + n], p2[n]);
            }
        }
        float a = bp3[0];
#pragma unroll
        for (int k = 0; k < 16; ++k) a = fmaf(fmaxf(p2[k], 0.0f), wp3[k], a);
        if (j == 0) ap0 = a; else if (j == 1) ap1 = a; else if (j == 2) ap2 = a; else ap3 = a;
    }
    const float am = 0.25f * (ap0 + ap1 + ap2 + ap3);
    float* __restrict__ o = out + (long long)row * 5;
    o[0] = value + a_shoot;
    o[1] = value + ap0 - am;
    o[2] = value + ap1 - am;
    o[3] = value + ap2 - am;
    o[4] = value + ap3 - am;
}

extern "C" void kernel_launch(void* const* d_in, const int* in_sizes, int n_in,
                              void* d_out, int out_size, void* d_ws, size_t ws_size,
                              hipStream_t stream) {
    const float* state = (const float*)d_in[0];
    const float* emb   = (const float*)d_in[1];
    const float* wd1 = (const float*)d_in[2];  const float* bd1 = (const float*)d_in[3];
    const float* wd2 = (const float*)d_in[4];  const float* bd2 = (const float*)d_in[5];
    const float* wt1 = (const float*)d_in[6];  const float* bt1 = (const float*)d_in[7];
    const float* wt2 = (const float*)d_in[8];  const float* bt2 = (const float*)d_in[9];
    const float* wv1 = (const float*)d_in[10]; const float* bv1 = (const float*)d_in[11];
    const float* wv2 = (const float*)d_in[12]; const float* bv2 = (const float*)d_in[13];
    const float* wv3 = (const float*)d_in[14]; const float* bv3 = (const float*)d_in[15];
    const float* ws1 = (const float*)d_in[16]; const float* bs1 = (const float*)d_in[17];
    const float* ws2 = (const float*)d_in[18]; const float* bs2 = (const float*)d_in[19];
    const float* wp1 = (const float*)d_in[20]; const float* bp1 = (const float*)d_in[21];
    const float* wp2 = (const float*)d_in[22]; const float* bp2 = (const float*)d_in[23];
    const float* wp3 = (const float*)d_in[24]; const float* bp3 = (const float*)d_in[25];

    const int nrows = in_sizes[0] / 78;

    if (ws_size < (size_t)WS_BYTES || (nrows & 127) != 0) {
        const int blocks = (nrows + 255) / 256;
        dueling_fwd_valu<<<blocks, 256, 0, stream>>>(
            state, emb, wd1, bd1, wd2, bd2, wt1, bt1, wt2, bt2,
            wv1, bv1, wv2, bv2, wv3, bv3, ws1, bs1, ws2, bs2,
            wp1, bp1, wp2, bp2, wp3, bp3, (float*)d_out, nrows);
        return;
    }

    prep_weights<<<36, 64, 0, stream>>>(wd2, wt1, wt2, wp1, wp2, wv1, wv2, ws1,
                                        (uint4*)d_ws);
    dueling_mfma<<<nrows / 128, THREADS, 0, stream>>>(
        state, emb, wd1, bd1, bd2, bt1, bt2, bv1, bv2, wv3, bv3,
        bs1, ws2, bs2, bp1, bp2, wp3,
        (const uint4*)d_ws, (float*)d_out, nrows);
}